// Round 2
// baseline (103.432 us; speedup 1.0000x reference)
//
#include <hip/hip_runtime.h>
#include <math.h>

// ws layout (doubles):
//   [0 .. 16*B)            stage-A per-batch sums: W, Sp[3], Sg[3], P[9]
//   [16*B .. 32*B)         stage-2 per-batch: R[9], mu_pred[3], mu_gt[3], W
//   [32*B]                 align_sum accumulator
//   [32*B+1]               bond_sum accumulator

#define RT 256   // rows per block (= threads)
#define CT 64    // cols per LDS tile

__global__ void k_stats(const float* __restrict__ pred, const float* __restrict__ gt,
                        const float* __restrict__ w, double* __restrict__ ws, int N) {
    int b = blockIdx.x;
    const float* p  = pred + (size_t)b * N * 3;
    const float* g  = gt   + (size_t)b * N * 3;
    const float* wb = w    + (size_t)b * N;

    double acc[16];
    #pragma unroll
    for (int i = 0; i < 16; i++) acc[i] = 0.0;

    for (int n = threadIdx.x; n < N; n += blockDim.x) {
        double wn = wb[n];
        double px = p[3*n], py = p[3*n+1], pz = p[3*n+2];
        double gx = g[3*n], gy = g[3*n+1], gz = g[3*n+2];
        acc[0] += wn;
        acc[1] += wn*px; acc[2] += wn*py; acc[3] += wn*pz;
        acc[4] += wn*gx; acc[5] += wn*gy; acc[6] += wn*gz;
        acc[7]  += wn*px*gx; acc[8]  += wn*px*gy; acc[9]  += wn*px*gz;
        acc[10] += wn*py*gx; acc[11] += wn*py*gy; acc[12] += wn*py*gz;
        acc[13] += wn*pz*gx; acc[14] += wn*pz*gy; acc[15] += wn*pz*gz;
    }

    // wave (64-lane) reduction
    #pragma unroll
    for (int off = 32; off > 0; off >>= 1) {
        #pragma unroll
        for (int i = 0; i < 16; i++) acc[i] += __shfl_down(acc[i], off, 64);
    }

    __shared__ double sh[4][16];
    int wave = threadIdx.x >> 6, lane = threadIdx.x & 63;
    if (lane == 0) {
        #pragma unroll
        for (int i = 0; i < 16; i++) sh[wave][i] = acc[i];
    }
    __syncthreads();
    if (threadIdx.x == 0) {
        int nw = blockDim.x >> 6;
        for (int i = 0; i < 16; i++) {
            double s = 0.0;
            for (int wv = 0; wv < nw; wv++) s += sh[wv][i];
            ws[b * 16 + i] = s;
        }
    }
}

// One thread per batch: build M, Jacobi-eigendecompose M^T M, construct Kabsch R.
__global__ void k_svd(double* __restrict__ ws, int B) {
    int b = threadIdx.x;
    if (b == 0) { ws[32*B] = 0.0; ws[32*B + 1] = 0.0; }  // zero accumulators
    if (b >= B) return;

    const double* s = ws + b * 16;
    double W = s[0];
    double mup[3] = { s[1]/W, s[2]/W, s[3]/W };
    double mug[3] = { s[4]/W, s[5]/W, s[6]/W };
    double M[3][3];
    for (int i = 0; i < 3; i++)
        for (int j = 0; j < 3; j++)
            M[i][j] = s[7 + i*3 + j] - W * mup[i] * mug[j];

    // A = M^T M (symmetric PSD)
    double A[3][3];
    for (int i = 0; i < 3; i++)
        for (int j = 0; j < 3; j++) {
            double t = 0.0;
            for (int k = 0; k < 3; k++) t += M[k][i] * M[k][j];
            A[i][j] = t;
        }

    double V[3][3] = {{1,0,0},{0,1,0},{0,0,1}};
    for (int sweep = 0; sweep < 12; sweep++) {
        for (int pq = 0; pq < 3; pq++) {
            int p = (pq == 2) ? 1 : 0;
            int q = (pq == 0) ? 1 : 2;
            double apq = A[p][q];
            if (fabs(apq) < 1e-300) continue;
            double app = A[p][p], aqq = A[q][q];
            double theta = (aqq - app) / (2.0 * apq);
            double t = copysign(1.0, theta) / (fabs(theta) + sqrt(theta*theta + 1.0));
            double c = 1.0 / sqrt(t*t + 1.0), sn = t * c;
            A[p][p] = app - t * apq;
            A[q][q] = aqq + t * apq;
            A[p][q] = A[q][p] = 0.0;
            int r = 3 - p - q;
            double arp = A[r][p], arq = A[r][q];
            A[r][p] = A[p][r] = c*arp - sn*arq;
            A[r][q] = A[q][r] = sn*arp + c*arq;
            for (int rr = 0; rr < 3; rr++) {
                double vp = V[rr][p], vq = V[rr][q];
                V[rr][p] = c*vp - sn*vq;
                V[rr][q] = sn*vp + c*vq;
            }
        }
    }
    double d[3] = { A[0][0], A[1][1], A[2][2] };

    // sort eigenpairs descending (jnp SVD returns descending singular values;
    // the det-fix must flip the SMALLEST singular direction)
    int idx[3] = {0, 1, 2};
    for (int i = 0; i < 2; i++)
        for (int j = i + 1; j < 3; j++)
            if (d[idx[j]] > d[idx[i]]) { int tt = idx[i]; idx[i] = idx[j]; idx[j] = tt; }

    double u[3][3], v[3][3];  // u[i]/v[i] = i-th left/right singular vector
    for (int i = 0; i < 3; i++) {
        int c_ = idx[i];
        double sv = sqrt(fmax(d[c_], 0.0));
        double inv = (sv > 1e-12) ? 1.0 / sv : 0.0;
        for (int r = 0; r < 3; r++) v[i][r] = V[r][c_];
        for (int r = 0; r < 3; r++) {
            double t = 0.0;
            for (int k = 0; k < 3; k++) t += M[r][k] * v[i][k];
            u[i][r] = t * inv;
        }
    }

    double detM = M[0][0]*(M[1][1]*M[2][2] - M[1][2]*M[2][1])
                - M[0][1]*(M[1][0]*M[2][2] - M[1][2]*M[2][0])
                + M[0][2]*(M[1][0]*M[2][1] - M[1][1]*M[2][0]);
    double sg2 = (detM < 0.0) ? -1.0 : 1.0;

    double* o = ws + 16*B + b*16;
    for (int r = 0; r < 3; r++)
        for (int cc = 0; cc < 3; cc++)
            o[r*3 + cc] = u[0][r]*v[0][cc] + u[1][r]*v[1][cc] + sg2 * u[2][r]*v[2][cc];
    for (int i = 0; i < 3; i++) o[9 + i]  = mup[i];
    for (int i = 0; i < 3; i++) o[12 + i] = mug[i];
    o[15] = W;
}

__global__ void k_pair(const float* __restrict__ pred, const float* __restrict__ gt,
                       const float* __restrict__ w, double* __restrict__ ws,
                       int N, int B) {
    int b  = blockIdx.z;
    int n  = blockIdx.x * RT + threadIdx.x;
    int c0 = blockIdx.y * CT;
    const float* p  = pred + (size_t)b * N * 3;
    const float* g  = gt   + (size_t)b * N * 3;
    const float* wb = w    + (size_t)b * N;

    __shared__ float sp[CT][3], sg[CT][3], sw[CT];
    for (int i = threadIdx.x; i < CT; i += blockDim.x) {
        int m = c0 + i;
        if (m < N) {
            sp[i][0] = p[3*m]; sp[i][1] = p[3*m+1]; sp[i][2] = p[3*m+2];
            sg[i][0] = g[3*m]; sg[i][1] = g[3*m+1]; sg[i][2] = g[3*m+2];
            sw[i] = wb[m];
        } else {
            sp[i][0] = sp[i][1] = sp[i][2] = 0.0f;
            sg[i][0] = sg[i][1] = sg[i][2] = 0.0f;
            sw[i] = 0.0f;
        }
    }
    __syncthreads();

    float  bond_f  = 0.0f;
    double align_d = 0.0;
    if (n < N) {
        float px = p[3*n], py = p[3*n+1], pz = p[3*n+2];
        float gx = g[3*n], gy = g[3*n+1], gz = g[3*n+2];
        float wn = wb[n];
        int cc = min(CT, N - c0);
        for (int i = 0; i < cc; i++) {
            float dxp = px - sp[i][0], dyp = py - sp[i][1], dzp = pz - sp[i][2];
            float dp  = sqrtf(dxp*dxp + dyp*dyp + dzp*dzp);
            float dxg = gx - sg[i][0], dyg = gy - sg[i][1], dzg = gz - sg[i][2];
            float dg  = sqrtf(dxg*dxg + dyg*dyg + dzg*dzg);
            float dd  = dp - dg;
            bond_f += wn * sw[i] * dd * dd;
        }
        if (blockIdx.y == 0) {
            const double* o = ws + 16*B + b*16;
            double xc0 = (double)gx - o[12], xc1 = (double)gy - o[13], xc2 = (double)gz - o[14];
            double ax = o[0]*xc0 + o[1]*xc1 + o[2]*xc2 + o[9];
            double ay = o[3]*xc0 + o[4]*xc1 + o[5]*xc2 + o[10];
            double az = o[6]*xc0 + o[7]*xc1 + o[8]*xc2 + o[11];
            double ex = (double)px - ax, ey = (double)py - ay, ez = (double)pz - az;
            double sq = ex*ex + ey*ey + ez*ez;
            align_d = (sq > 0.0) ? (double)wn * sqrt(sq) : 0.0;
        }
    }

    double bd = (double)bond_f;
    #pragma unroll
    for (int off = 32; off > 0; off >>= 1) {
        bd      += __shfl_down(bd, off, 64);
        align_d += __shfl_down(align_d, off, 64);
    }
    __shared__ double shb[4], sha[4];
    int wave = threadIdx.x >> 6, lane = threadIdx.x & 63;
    if (lane == 0) { shb[wave] = bd; sha[wave] = align_d; }
    __syncthreads();
    if (threadIdx.x == 0) {
        int nw = blockDim.x >> 6;
        double bt = 0.0, at = 0.0;
        for (int wv = 0; wv < nw; wv++) { bt += shb[wv]; at += sha[wv]; }
        if (at != 0.0) atomicAdd(&ws[32*B], at);
        atomicAdd(&ws[32*B + 1], bt);
    }
}

__global__ void k_final(const float* __restrict__ ht, const double* __restrict__ ws,
                        float* __restrict__ out, int B) {
    int b = threadIdx.x;
    if (b >= B) return;
    double tw = 0.0, twp = 0.0;
    for (int i = 0; i < B; i++) {
        double W = ws[16*B + i*16 + 15];
        tw  += W;
        twp += W * W;
    }
    double loss = ws[32*B] / tw + ws[32*B + 1] / twp;  // ALPHA_BOND = 1
    double h = ht[b];
    double scale = (h*h + 256.0) / ((h + 16.0) * (h + 16.0));  // SIGMA_DATA = 16
    out[b] = (float)(scale * loss);
}

extern "C" void kernel_launch(void* const* d_in, const int* in_sizes, int n_in,
                              void* d_out, int out_size, void* d_ws, size_t ws_size,
                              hipStream_t stream) {
    const float* pred = (const float*)d_in[0];  // xpred_l [B,N,3]
    const float* gt   = (const float*)d_in[1];  // xGT_l   [B,N,3]
    const float* ht   = (const float*)d_in[2];  // ht      [B]
    const float* w    = (const float*)d_in[3];  // w_l     [B,N]
    int B = in_sizes[2];
    int N = in_sizes[3] / B;
    double* ws = (double*)d_ws;
    float* out = (float*)d_out;

    k_stats<<<dim3(B), dim3(256), 0, stream>>>(pred, gt, w, ws, N);
    k_svd<<<dim3(1), dim3(64), 0, stream>>>(ws, B);
    dim3 g3((N + RT - 1) / RT, (N + CT - 1) / CT, B);
    k_pair<<<g3, dim3(RT), 0, stream>>>(pred, gt, w, ws, N, B);
    k_final<<<dim3(1), dim3(64), 0, stream>>>(ht, ws, out, B);
}